// Round 13
// baseline (797.761 us; speedup 1.0000x reference)
//
#include <hip/hip_runtime.h>
#include <hip/hip_cooperative_groups.h>
#include <math.h>

namespace cg = cooperative_groups;

#define H 128

typedef _Float16 half8 __attribute__((ext_vector_type(8)));
typedef float f32x16 __attribute__((ext_vector_type(16)));
typedef int int4v __attribute__((ext_vector_type(4)));

__device__ __forceinline__ half8 h8max(half8 a, half8 b) {
#if defined(__has_builtin) && __has_builtin(__builtin_elementwise_max)
    return __builtin_elementwise_max(a, b);
#else
    half8 r;
#pragma unroll
    for (int j = 0; j < 8; ++j) r[j] = a[j] > b[j] ? a[j] : b[j];
    return r;
#endif
}

__device__ __forceinline__ half8 h8shfl_xor(half8 v, int mask) {
    int4v iv;
    __builtin_memcpy(&iv, &v, 16);
#pragma unroll
    for (int j = 0; j < 4; ++j) iv[j] = __shfl_xor(iv[j], mask, 64);
    half8 r;
    __builtin_memcpy(&r, &iv, 16);
    return r;
}

// ============================================================================
// Shared tile bodies (used by both the mega kernel and the fallback kernels)
// ============================================================================

// ---- one 64-row fused layer tile: hi-gather-max + dual GEMM + bias + relu --
// LDS: sU 16 KB (m full-K image / x 64-k chunk) + sB 16 KB at smem+16384.
__device__ __forceinline__ void layer_tile(
    char* smem, int n0, const half8* __restrict__ Xh,
    const int* __restrict__ deg, const int* __restrict__ offsets,
    const int* __restrict__ adj, const _Float16* __restrict__ Bimg,
    const float* __restrict__ bias, _Float16* __restrict__ Yh, int N,
    bool firstTile) {
    _Float16* sU = (_Float16*)smem;
    _Float16* sB = (_Float16*)(smem + 16384);

    int tid = threadIdx.x;
    int w = tid >> 6;
    int lane = tid & 63;
    int l31 = lane & 31;
    int lhi = lane >> 5;
    int ws = w >> 1;  // row stripe (32 rows)
    int wc = w & 1;   // col half (64 cols)

    if (!firstTile) __syncthreads();  // protect LDS reuse across tiles

    // ---- Phase G: wave-per-node hi-only gather segment-max ----
    {
        int sub = lane >> 4;  // neighbor slot 0..3
        int lf = lane & 15;   // feature granule
        const _Float16 ni = (_Float16)(-INFINITY);
        const half8 ninf = {ni, ni, ni, ni, ni, ni, ni, ni};
        const half8 hz = {(_Float16)0.f, (_Float16)0.f, (_Float16)0.f, (_Float16)0.f,
                          (_Float16)0.f, (_Float16)0.f, (_Float16)0.f, (_Float16)0.f};
        int nd = n0 + w * 16 + lf;
        int ndc = nd < N ? nd : N - 1;
        int e0v = offsets[ndc];
        int degv = (nd < N) ? deg[ndc] : 0;

        for (int i = 0; i < 16; ++i) {
            int e0 = __shfl(e0v, i, 64);
            int d = __shfl(degv, i, 64);
            int row = w * 16 + i;
            half8 acc = ninf;
            for (int base = 0; base < d; base += 16) {
                half8 v[4];
#pragma unroll
                for (int q = 0; q < 4; ++q) {
                    int j = base + q * 4 + sub;
                    int idx = adj[e0 + (j < d ? j : d - 1)];
                    v[q] = Xh[(size_t)idx * 16 + lf];
                }
                acc = h8max(acc, h8max(h8max(v[0], v[1]), h8max(v[2], v[3])));
            }
            acc = h8max(acc, h8shfl_xor(acc, 16));
            acc = h8max(acc, h8shfl_xor(acc, 32));
            if (d == 0) acc = hz;
            if (sub == 0) *(half8*)&sU[row * 128 + (lf ^ (row & 15)) * 8] = acc;
        }
    }
    __syncthreads();

    f32x16 acc[2];
#pragma unroll
    for (int nt = 0; nt < 2; ++nt) {
        float bv = bias[wc * 64 + nt * 32 + l31];
#pragma unroll
        for (int r = 0; r < 16; ++r) acc[nt][r] = bv;
    }

    int rl = ws * 32 + l31;

    // ---- Pass 0: m @ Wl^T ----
    for (int kc4 = 0; kc4 < 4; ++kc4) {
        if (kc4) __syncthreads();
        {
            const half8* bsrc = (const half8*)(Bimg + (size_t)kc4 * 8192);
            half8* bdst = (half8*)sB;
#pragma unroll
            for (int i = 0; i < 4; ++i) bdst[tid + i * 256] = bsrc[tid + i * 256];
        }
        __syncthreads();
#pragma unroll
        for (int ks = 0; ks < 2; ++ks) {
            int g16 = kc4 * 4 + ks * 2 + lhi;
            int posA = g16 ^ (rl & 15);
            half8 ah = *(const half8*)&sU[rl * 128 + posA * 8];
#pragma unroll
            for (int nt = 0; nt < 2; ++nt) {
                int n = wc * 64 + nt * 32 + l31;
                int gpc = ks * 2 + lhi;
                int posB = (gpc + (n & 3) + ((n >> 2) & 3)) & 3;
                half8 bh = *(const half8*)&sB[n * 32 + posB * 8];
                half8 bl2 = *(const half8*)&sB[4096 + n * 32 + posB * 8];
                acc[nt] = __builtin_amdgcn_mfma_f32_32x32x16_f16(ah, bh, acc[nt], 0, 0, 0);
                acc[nt] = __builtin_amdgcn_mfma_f32_32x32x16_f16(ah, bl2, acc[nt], 0, 0, 0);
            }
        }
    }

    // ---- Pass 1: x @ Wr^T ----
    for (int kc4 = 0; kc4 < 4; ++kc4) {
        __syncthreads();
        {
            const half8* bsrc = (const half8*)(Bimg + 32768 + (size_t)kc4 * 8192);
            half8* bdst = (half8*)sB;
#pragma unroll
            for (int i = 0; i < 4; ++i) bdst[tid + i * 256] = bsrc[tid + i * 256];
        }
        if ((kc4 & 1) == 0) {
            int kc64 = kc4 >> 1;
#pragma unroll
            for (int i = 0; i < 2; ++i) {
                int idx = tid + i * 256;  // [0,512)
                int row = idx >> 3;       // [0,64)
                int gp8 = idx & 7;
                int n = n0 + row;
                half8 h = {(_Float16)0.f, (_Float16)0.f, (_Float16)0.f, (_Float16)0.f,
                           (_Float16)0.f, (_Float16)0.f, (_Float16)0.f, (_Float16)0.f};
                if (n < N) h = Xh[(size_t)n * 16 + kc64 * 8 + gp8];
                int pos8 = (gp8 + (row & 7) + ((row >> 3) & 7)) & 7;
                *(half8*)&sU[row * 72 + pos8 * 8] = h;
            }
        }
        __syncthreads();
#pragma unroll
        for (int ks = 0; ks < 2; ++ks) {
            int gp8 = (kc4 & 1) * 4 + ks * 2 + lhi;
            int posA8 = (gp8 + (rl & 7) + ((rl >> 3) & 7)) & 7;
            half8 ah = *(const half8*)&sU[rl * 72 + posA8 * 8];
#pragma unroll
            for (int nt = 0; nt < 2; ++nt) {
                int n = wc * 64 + nt * 32 + l31;
                int gpc = ks * 2 + lhi;
                int posB = (gpc + (n & 3) + ((n >> 2) & 3)) & 3;
                half8 bh = *(const half8*)&sB[n * 32 + posB * 8];
                half8 bl2 = *(const half8*)&sB[4096 + n * 32 + posB * 8];
                acc[nt] = __builtin_amdgcn_mfma_f32_32x32x16_f16(ah, bh, acc[nt], 0, 0, 0);
                acc[nt] = __builtin_amdgcn_mfma_f32_32x32x16_f16(ah, bl2, acc[nt], 0, 0, 0);
            }
        }
    }

    // epilogue: relu + fp16 store
#pragma unroll
    for (int r = 0; r < 16; ++r) {
        int row = n0 + ws * 32 + (r & 3) + 8 * (r >> 2) + 4 * lhi;
        if (row < N) {
#pragma unroll
            for (int nt = 0; nt < 2; ++nt) {
                int col = wc * 64 + nt * 32 + l31;
                Yh[(size_t)row * H + col] = (_Float16)fmaxf(acc[nt][r], 0.f);
            }
        }
    }
}

// ---- one 128-row final tile: linear + cosine ----
// LDS: sA 18 KB (stride-72), sB 16 KB at smem+18432 (34816 B total).
__device__ __forceinline__ void final_tile(
    char* smem, int n0, const half8* __restrict__ Xh,
    const _Float16* __restrict__ Bimg, const float* __restrict__ blin,
    const float* __restrict__ qn, const int* __restrict__ bv,
    float* __restrict__ out, int N, bool firstTile) {
    _Float16* sA = (_Float16*)smem;
    _Float16* sB = (_Float16*)(smem + 18432);

    int tid = threadIdx.x;
    int w = tid >> 6;
    int lane = tid & 63;
    int l31 = lane & 31;
    int lhi = lane >> 5;

    if (!firstTile) __syncthreads();

    int arow = n0 + w * 32 + l31;
    arow = arow < N ? arow : N - 1;
    int gl = bv[arow];

    f32x16 acc[4];
#pragma unroll
    for (int nt = 0; nt < 4; ++nt) {
        float b = blin[nt * 32 + l31];
#pragma unroll
        for (int r = 0; r < 16; ++r) acc[nt][r] = b;
    }

    int rl = w * 32 + l31;

    for (int kc4 = 0; kc4 < 4; ++kc4) {
        if (kc4) __syncthreads();
        {
            const half8* bsrc = (const half8*)(Bimg + (size_t)kc4 * 8192);
            half8* bdst = (half8*)sB;
#pragma unroll
            for (int i = 0; i < 4; ++i) bdst[tid + i * 256] = bsrc[tid + i * 256];
        }
        if ((kc4 & 1) == 0) {
            int kc64 = kc4 >> 1;
#pragma unroll
            for (int i = 0; i < 4; ++i) {
                int idx = tid + i * 256;  // [0,1024)
                int row = idx >> 3;       // [0,128)
                int gp8 = idx & 7;
                int n = n0 + row;
                half8 h = {(_Float16)0.f, (_Float16)0.f, (_Float16)0.f, (_Float16)0.f,
                           (_Float16)0.f, (_Float16)0.f, (_Float16)0.f, (_Float16)0.f};
                if (n < N) h = Xh[(size_t)n * 16 + kc64 * 8 + gp8];
                int pos8 = (gp8 + (row & 7) + ((row >> 3) & 7)) & 7;
                *(half8*)&sA[row * 72 + pos8 * 8] = h;
            }
        }
        __syncthreads();
#pragma unroll
        for (int ks = 0; ks < 2; ++ks) {
            int gp8 = (kc4 & 1) * 4 + ks * 2 + lhi;
            int posA8 = (gp8 + (rl & 7) + ((rl >> 3) & 7)) & 7;
            half8 ah = *(const half8*)&sA[rl * 72 + posA8 * 8];
#pragma unroll
            for (int nt = 0; nt < 4; ++nt) {
                int n = nt * 32 + l31;
                int gpc = ks * 2 + lhi;
                int posB = (gpc + (n & 3) + ((n >> 2) & 3)) & 3;
                half8 bh = *(const half8*)&sB[n * 32 + posB * 8];
                half8 bl2 = *(const half8*)&sB[4096 + n * 32 + posB * 8];
                acc[nt] = __builtin_amdgcn_mfma_f32_32x32x16_f16(ah, bh, acc[nt], 0, 0, 0);
                acc[nt] = __builtin_amdgcn_mfma_f32_32x32x16_f16(ah, bl2, acc[nt], 0, 0, 0);
            }
        }
    }

#pragma unroll
    for (int r = 0; r < 16; ++r) {
        int rloc = (r & 3) + 8 * (r >> 2) + 4 * lhi;
        int row = n0 + w * 32 + rloc;
        int g = __shfl(gl, rloc, 32);
        float ss = 0.f, sd = 0.f;
#pragma unroll
        for (int nt = 0; nt < 4; ++nt) {
            float y = acc[nt][r];
            float q = qn[(size_t)g * H + nt * 32 + l31];
            ss = fmaf(y, y, ss);
            sd = fmaf(y, q, sd);
        }
#pragma unroll
        for (int off = 1; off <= 16; off <<= 1) {
            ss += __shfl_xor(ss, off, 64);
            sd += __shfl_xor(sd, off, 64);
        }
        if (l31 == 0 && row < N) out[row] = sd / fmaxf(sqrtf(ss), 1e-12f);
    }
}

// ---- prep body (grid-strided role switch) ----
__device__ __forceinline__ void prep_body(
    char* smem, int b, int tid, const int* __restrict__ ei, int E,
    int* __restrict__ deg, const float* __restrict__ x,
    const float* __restrict__ query, const float* __restrict__ Wl,
    const float* __restrict__ Wr, const float* __restrict__ Wlin,
    _Float16* __restrict__ xh, _Float16* __restrict__ wimg,
    float* __restrict__ qn, int n8, int HB, int SB, int WB) {
    if (b < HB) {
        int e = b * 256 + tid;
        if (e < E) atomicAdd(&deg[ei[E + e]], 1);
    } else if (b < HB + SB) {
        int i = (b - HB) * 256 + tid;
        if (i < n8) {
            const float4* x4 = (const float4*)x;
            float4 u = x4[(size_t)i * 2], v = x4[(size_t)i * 2 + 1];
            float f[8] = {u.x, u.y, u.z, u.w, v.x, v.y, v.z, v.w};
            half8 h;
#pragma unroll
            for (int j = 0; j < 8; ++j) h[j] = (_Float16)f[j];
            *(half8*)(xh + (size_t)i * 8) = h;
        }
    } else if (b < HB + SB + WB) {
        int gidx = (b - HB - SB) * 256 + tid;
        if (gidx < 7 * 2048) {
            int mat = gidx / 2048;
            int rem = gidx - mat * 2048;
            int n = rem >> 4;
            int g = rem & 15;
            const float* src = (mat == 6) ? Wlin
                             : ((mat & 1) ? Wr + (mat >> 1) * H * H
                                          : Wl + (mat >> 1) * H * H);
            const float* p = src + n * H + g * 8;
            half8 h, l;
#pragma unroll
            for (int j = 0; j < 8; ++j) {
                float v = p[j];
                _Float16 hh = (_Float16)v;
                h[j] = hh;
                l[j] = (_Float16)(v - (float)hh);
            }
            int kc4 = g >> 2, gpc = g & 3;
            int posB = (gpc + (n & 3) + ((n >> 2) & 3)) & 3;
            size_t base = (size_t)mat * 32768 + (size_t)kc4 * 8192 + n * 32 + posB * 8;
            *(half8*)(wimg + base) = h;
            *(half8*)(wimg + base + 4096) = l;
        }
    } else {
        int g = b - HB - SB - WB;
        float* part = (float*)smem;
        float v = (tid < 128) ? query[g * H + tid] : 0.f;
        float ss = v * v;
#pragma unroll
        for (int off = 32; off > 0; off >>= 1) ss += __shfl_xor(ss, off, 64);
        if ((tid & 63) == 0) part[tid >> 6] = ss;
        __syncthreads();
        float tot = part[0] + part[1];
        if (tid < 128) qn[g * H + tid] = v / fmaxf(sqrtf(tot), 1e-12f);
        __syncthreads();
    }
}

// ============================================================================
// Cooperative mega-kernel
// ============================================================================

__global__ __launch_bounds__(256, 4) void mega(
    const int* __restrict__ ei, int E, int* __restrict__ deg,
    int* __restrict__ cursor, int* __restrict__ gcur,
    int* __restrict__ offsets, int* __restrict__ adj,
    const float* __restrict__ x, const float* __restrict__ query,
    const float* __restrict__ Wl, const float* __restrict__ bl,
    const float* __restrict__ Wr, const float* __restrict__ Wlin,
    const float* __restrict__ blin, const int* __restrict__ bv,
    _Float16* __restrict__ xa, _Float16* __restrict__ xb,
    _Float16* __restrict__ wimg, float* __restrict__ qn,
    float* __restrict__ out, int N, int G) {
    cg::grid_group grid = cg::this_grid();
    __shared__ __align__(16) char smem[34816];
    int tid = threadIdx.x;
    const int nblk = gridDim.x;

    // ---- phase 0: deg hist + x->fp16 + weight images + query norm ----
    {
        int n8 = N * (H / 8);
        int HB = (E + 255) >> 8;
        int SB = (n8 + 255) >> 8;
        int WB = (7 * 2048 + 255) >> 8;
        int U0 = HB + SB + WB + G;
        for (int b = blockIdx.x; b < U0; b += nblk)
            prep_body(smem, b, tid, ei, E, deg, x, query, Wl, Wr, Wlin, xa, wimg,
                      qn, n8, HB, SB, WB);
    }
    grid.sync();

    // ---- phase 1: unordered exclusive scan ----
    {
        int U1 = (N + 255) >> 8;
        int* buf = (int*)smem;
        int* sbase = (int*)(smem + 1024);
        for (int b = blockIdx.x; b < U1; b += nblk) {
            int i = b * 256 + tid;
            int v = (i < N) ? deg[i] : 0;
            int incl = v;
            buf[tid] = v;
            __syncthreads();
#pragma unroll
            for (int off = 1; off < 256; off <<= 1) {
                int t = (tid >= off) ? buf[tid - off] : 0;
                __syncthreads();
                incl += t;
                buf[tid] = incl;
                __syncthreads();
            }
            if (tid == 255) *sbase = atomicAdd(gcur, incl);
            __syncthreads();
            if (i < N) offsets[i] = *sbase + incl - v;
            __syncthreads();
        }
    }
    grid.sync();

    // ---- phase 2: fill adjacency ----
    {
        int U2 = (E + 255) >> 8;
        for (int b = blockIdx.x; b < U2; b += nblk) {
            int e = b * 256 + tid;
            if (e < E) {
                int s = ei[e];
                int d = ei[E + e];
                int pos = atomicAdd(&cursor[d], 1);
                adj[offsets[d] + pos] = s;
            }
        }
    }
    grid.sync();

    // ---- phases 3..5: three fused layers ----
    int NT = (N + 63) >> 6;
    {
        bool first = true;
        for (int b = blockIdx.x; b < NT; b += nblk, first = false)
            layer_tile((char*)smem, b * 64, (const half8*)xa, deg, offsets, adj,
                       wimg + (size_t)0 * 65536, bl + 0 * H, xb, N, first);
    }
    grid.sync();
    {
        bool first = true;
        for (int b = blockIdx.x; b < NT; b += nblk, first = false)
            layer_tile((char*)smem, b * 64, (const half8*)xb, deg, offsets, adj,
                       wimg + (size_t)1 * 65536, bl + 1 * H, xa, N, first);
    }
    grid.sync();
    {
        bool first = true;
        for (int b = blockIdx.x; b < NT; b += nblk, first = false)
            layer_tile((char*)smem, b * 64, (const half8*)xa, deg, offsets, adj,
                       wimg + (size_t)2 * 65536, bl + 2 * H, xb, N, first);
    }
    grid.sync();

    // ---- phase 6: final linear + cosine ----
    int NF = (N + 127) >> 7;
    {
        bool first = true;
        for (int b = blockIdx.x; b < NF; b += nblk, first = false)
            final_tile((char*)smem, b * 128, (const half8*)xb,
                       wimg + (size_t)6 * 32768, blin, qn, bv, out, N, first);
    }
}

// ============================================================================
// Fallback kernels (R11 path)
// ============================================================================

__global__ __launch_bounds__(256) void scan_atomic(const int* __restrict__ deg,
                                                   int* __restrict__ offsets,
                                                   int* __restrict__ gcur, int N) {
    __shared__ int buf[256];
    __shared__ int sbase;
    int tid = threadIdx.x;
    int i = blockIdx.x * 256 + tid;
    int v = (i < N) ? deg[i] : 0;
    int incl = v;
    buf[tid] = v;
    __syncthreads();
#pragma unroll
    for (int off = 1; off < 256; off <<= 1) {
        int t = (tid >= off) ? buf[tid - off] : 0;
        __syncthreads();
        incl += t;
        buf[tid] = incl;
        __syncthreads();
    }
    if (tid == 255) sbase = atomicAdd(gcur, incl);
    __syncthreads();
    if (i < N) offsets[i] = sbase + incl - v;
}

__global__ __launch_bounds__(256) void fill_adj_k(const int* __restrict__ ei, int E,
                                                  const int* __restrict__ offsets,
                                                  int* __restrict__ cursor,
                                                  int* __restrict__ adj) {
    int e = blockIdx.x * 256 + threadIdx.x;
    if (e < E) {
        int s = ei[e];
        int d = ei[E + e];
        int pos = atomicAdd(&cursor[d], 1);
        adj[offsets[d] + pos] = s;
    }
}

__global__ __launch_bounds__(256) void prep_all_k(
    const int* __restrict__ ei, int E, int* __restrict__ deg,
    const float* __restrict__ x, const float* __restrict__ query,
    const float* __restrict__ Wl, const float* __restrict__ Wr,
    const float* __restrict__ Wlin, _Float16* __restrict__ xh,
    _Float16* __restrict__ wimg, float* __restrict__ qn, int n8, int HB, int SB,
    int WB) {
    __shared__ __align__(16) char smem[1024];
    prep_body(smem, blockIdx.x, threadIdx.x, ei, E, deg, x, query, Wl, Wr, Wlin,
              xh, wimg, qn, n8, HB, SB, WB);
}

__global__ __launch_bounds__(256) void layer_k(
    const half8* __restrict__ Xh, const int* __restrict__ deg,
    const int* __restrict__ offsets, const int* __restrict__ adj,
    const _Float16* __restrict__ Bimg, const float* __restrict__ bias,
    _Float16* __restrict__ Yh, int N) {
    __shared__ __align__(16) char smem[32768];
    layer_tile(smem, blockIdx.x * 64, Xh, deg, offsets, adj, Bimg, bias, Yh, N,
               true);
}

__global__ __launch_bounds__(256) void final_k(
    const half8* __restrict__ Xh, const _Float16* __restrict__ Bimg,
    const float* __restrict__ blin, const float* __restrict__ qn,
    const int* __restrict__ bv, float* __restrict__ out, int N) {
    __shared__ __align__(16) char smem[34816];
    final_tile(smem, blockIdx.x * 128, Xh, Bimg, blin, qn, bv, out, N, true);
}

// ---------------- launch ----------------

extern "C" void kernel_launch(void* const* d_in, const int* in_sizes, int n_in,
                              void* d_out, int out_size, void* d_ws, size_t ws_size,
                              hipStream_t stream) {
    const float* x = (const float*)d_in[0];
    const float* query = (const float*)d_in[1];
    const float* Wl = (const float*)d_in[2];
    const float* bl = (const float*)d_in[3];
    const float* Wr = (const float*)d_in[4];
    const float* Wlin = (const float*)d_in[5];
    const float* blin = (const float*)d_in[6];
    const int* ei = (const int*)d_in[7];
    const int* bv = (const int*)d_in[8];
    float* out = (float*)d_out;

    const int N = in_sizes[0] / H;
    const int E = in_sizes[7] / 2;
    const int G = in_sizes[1] / H;

    char* p = (char*)d_ws;
    auto alloc = [&](size_t bytes) {
        char* r = p;
        p += (bytes + 255) & ~(size_t)255;
        return r;
    };
    int* deg = (int*)alloc((size_t)(2 * N + 1) * sizeof(int));  // deg|cursor|gcur
    int* cursor = deg + N;
    int* gcur = deg + 2 * N;
    int* offsets = (int*)alloc((size_t)N * sizeof(int));
    int* adj = (int*)alloc((size_t)E * sizeof(int));
    float* qn = (float*)alloc((size_t)G * H * sizeof(float));
    _Float16* wimg = (_Float16*)alloc((size_t)7 * 32768 * sizeof(_Float16));
    size_t actH = (size_t)N * H * sizeof(_Float16);
    _Float16* xah = (_Float16*)alloc(actH);
    _Float16* xbh = (_Float16*)alloc(actH);

    hipMemsetAsync(deg, 0, (size_t)(2 * N + 1) * sizeof(int), stream);

    const int n8 = N * H / 8;
    const int HB = (E + 255) / 256;
    const int SB = (n8 + 255) / 256;
    const int WB = (7 * 2048 + 255) / 256;

    // ---- try the cooperative single-launch path with runtime-validated grid --
    int maxPerCU = 0;
    hipError_t oe = hipOccupancyMaxActiveBlocksPerMultiprocessor(
        &maxPerCU, (const void*)mega, 256, 0);
    hipError_t le = hipErrorUnknown;
    if (oe == hipSuccess && maxPerCU >= 1) {
        int ngrid = maxPerCU * 256;  // 256 CUs on MI355X
        if (ngrid > 1024) ngrid = 1024;
        int E_ = E, N_ = N, G_ = G;
        const int* ei_ = ei;
        const float* x_ = x;
        const float* query_ = query;
        const float* Wl_ = Wl;
        const float* bl_ = bl;
        const float* Wr_ = Wr;
        const float* Wlin_ = Wlin;
        const float* blin_ = blin;
        const int* bv_ = bv;
        void* args[] = {(void*)&ei_,   (void*)&E_,      (void*)&deg,
                        (void*)&cursor, (void*)&gcur,   (void*)&offsets,
                        (void*)&adj,    (void*)&x_,     (void*)&query_,
                        (void*)&Wl_,    (void*)&bl_,    (void*)&Wr_,
                        (void*)&Wlin_,  (void*)&blin_,  (void*)&bv_,
                        (void*)&xah,    (void*)&xbh,    (void*)&wimg,
                        (void*)&qn,     (void*)&out,    (void*)&N_,
                        (void*)&G_};
        le = hipLaunchCooperativeKernel((const void*)mega, dim3(ngrid), dim3(256),
                                        args, 0, stream);
    }
    if (le == hipSuccess) return;

    // ---- fallback: proven multi-launch path (R11) ----
    prep_all_k<<<HB + SB + WB + G, 256, 0, stream>>>(ei, E, deg, x, query, Wl, Wr,
                                                     Wlin, xah, wimg, qn, n8, HB,
                                                     SB, WB);
    scan_atomic<<<(N + 255) / 256, 256, 0, stream>>>(deg, offsets, gcur, N);
    fill_adj_k<<<(E + 255) / 256, 256, 0, stream>>>(ei, E, offsets, cursor, adj);

    const int NGm = (N + 63) / 64;
    const int NGf = (N + 127) / 128;

    layer_k<<<NGm, 256, 0, stream>>>((const half8*)xah, deg, offsets, adj,
                                     wimg + (size_t)0 * 65536, bl + 0 * H, xbh, N);
    layer_k<<<NGm, 256, 0, stream>>>((const half8*)xbh, deg, offsets, adj,
                                     wimg + (size_t)1 * 65536, bl + 1 * H, xah, N);
    layer_k<<<NGm, 256, 0, stream>>>((const half8*)xah, deg, offsets, adj,
                                     wimg + (size_t)2 * 65536, bl + 2 * H, xbh, N);
    final_k<<<NGf, 256, 0, stream>>>((const half8*)xbh, wimg + (size_t)6 * 32768,
                                     blin, qn, bv, out, N);
}

// Round 14
// 288.524 us; speedup vs baseline: 2.7650x; 2.7650x over previous
//
#include <hip/hip_runtime.h>
#include <math.h>

#define H 128

typedef _Float16 half8 __attribute__((ext_vector_type(8)));
typedef float f32x16 __attribute__((ext_vector_type(16)));
typedef int int4v __attribute__((ext_vector_type(4)));

__device__ __forceinline__ half8 h8max(half8 a, half8 b) {
#if defined(__has_builtin) && __has_builtin(__builtin_elementwise_max)
    return __builtin_elementwise_max(a, b);
#else
    half8 r;
#pragma unroll
    for (int j = 0; j < 8; ++j) r[j] = a[j] > b[j] ? a[j] : b[j];
    return r;
#endif
}

__device__ __forceinline__ half8 h8shfl_xor(half8 v, int mask) {
    int4v iv;
    __builtin_memcpy(&iv, &v, 16);
#pragma unroll
    for (int j = 0; j < 4; ++j) iv[j] = __shfl_xor(iv[j], mask, 64);
    half8 r;
    __builtin_memcpy(&r, &iv, 16);
    return r;
}

// ---------------- CSR build ----------------

// Unordered exclusive allocation: block-scan + one atomicAdd for the base.
// Regions are disjoint [offsets[n], offsets[n]+deg[n]) but NOT index-ordered;
// all consumers use offsets[n] + deg[n], never offsets[n+1].
__global__ __launch_bounds__(256) void scan_atomic(const int* __restrict__ deg,
                                                   int* __restrict__ offsets,
                                                   int* __restrict__ gcur, int N) {
    __shared__ int buf[256];
    __shared__ int sbase;
    int tid = threadIdx.x;
    int i = blockIdx.x * 256 + tid;
    int v = (i < N) ? deg[i] : 0;
    int incl = v;
    buf[tid] = v;
    __syncthreads();
#pragma unroll
    for (int off = 1; off < 256; off <<= 1) {
        int t = (tid >= off) ? buf[tid - off] : 0;
        __syncthreads();
        incl += t;
        buf[tid] = incl;
        __syncthreads();
    }
    if (tid == 255) sbase = atomicAdd(gcur, incl);
    __syncthreads();
    if (i < N) offsets[i] = sbase + incl - v;
}

__global__ __launch_bounds__(256) void fill_adj(const int* __restrict__ ei, int E,
                                                const int* __restrict__ offsets,
                                                int* __restrict__ cursor,
                                                int* __restrict__ adj) {
    int e = blockIdx.x * 256 + threadIdx.x;
    if (e < E) {
        int s = ei[e];
        int d = ei[E + e];
        int pos = atomicAdd(&cursor[d], 1);
        adj[offsets[d] + pos] = s;
    }
}

// ---------------- merged prep: deg-hist, x->fp16, weight images, query ------
// Weight image per mat (order Wl0,Wr0,Wl1,Wr1,Wl2,Wr2,Wlin): 4 K-chunks of 32,
// each chunk: hi 4096 + lo 4096 halves. Chunk layout [n][posB*8], posB =
// (gpc + (n&3) + ((n>>2)&3)) & 3.

__global__ __launch_bounds__(256) void prep_all(
    const int* __restrict__ ei, int E, int* __restrict__ deg,
    const float* __restrict__ x, const float* __restrict__ query,
    const float* __restrict__ Wl, const float* __restrict__ Wr,
    const float* __restrict__ Wlin, _Float16* __restrict__ xh,
    _Float16* __restrict__ wimg, float* __restrict__ qn, int n8, int HB, int SB,
    int WB) {
    int b = blockIdx.x;
    int tid = threadIdx.x;
    if (b < HB) {
        // role 0: degree histogram
        int e = b * 256 + tid;
        if (e < E) atomicAdd(&deg[ei[E + e]], 1);
    } else if (b < HB + SB) {
        // role 1: x -> fp16 hi
        int i = (b - HB) * 256 + tid;
        if (i < n8) {
            const float4* x4 = (const float4*)x;
            float4 u = x4[(size_t)i * 2], v = x4[(size_t)i * 2 + 1];
            float f[8] = {u.x, u.y, u.z, u.w, v.x, v.y, v.z, v.w};
            half8 h;
#pragma unroll
            for (int j = 0; j < 8; ++j) h[j] = (_Float16)f[j];
            *(half8*)(xh + (size_t)i * 8) = h;
        }
    } else if (b < HB + SB + WB) {
        // role 2: weight split + chunk-image packing
        int gidx = (b - HB - SB) * 256 + tid;
        if (gidx < 7 * 2048) {
            int mat = gidx / 2048;
            int rem = gidx - mat * 2048;
            int n = rem >> 4;
            int g = rem & 15;
            const float* src = (mat == 6) ? Wlin
                             : ((mat & 1) ? Wr + (mat >> 1) * H * H
                                          : Wl + (mat >> 1) * H * H);
            const float* p = src + n * H + g * 8;
            half8 h, l;
#pragma unroll
            for (int j = 0; j < 8; ++j) {
                float v = p[j];
                _Float16 hh = (_Float16)v;
                h[j] = hh;
                l[j] = (_Float16)(v - (float)hh);
            }
            int kc4 = g >> 2, gpc = g & 3;
            int posB = (gpc + (n & 3) + ((n >> 2) & 3)) & 3;
            size_t base = (size_t)mat * 32768 + (size_t)kc4 * 8192 + n * 32 + posB * 8;
            *(half8*)(wimg + base) = h;
            *(half8*)(wimg + base + 4096) = l;
        }
    } else {
        // role 3: query normalization
        int g = b - HB - SB - WB;
        __shared__ float part[4];
        float v = (tid < 128) ? query[g * H + tid] : 0.f;
        float ss = v * v;
#pragma unroll
        for (int off = 32; off > 0; off >>= 1) ss += __shfl_xor(ss, off, 64);
        if ((tid & 63) == 0) part[tid >> 6] = ss;
        __syncthreads();
        float tot = part[0] + part[1];
        if (tid < 128) qn[g * H + tid] = v / fmaxf(sqrtf(tot), 1e-12f);
    }
}

// ---------------- fused layer, 32-row tile ----------------
// Y = relu(segmax(X) @ Wl^T + bias + X @ Wr^T), activations fp16 hi-only,
// weights split hi/lo (2 MFMAs per A-fragment).
// Block 256 = 4 waves; tile 32 rows x 128 cols (wave w owns cols w*32..+31).
// LDS: sU 8 KB (m full-K image / x chunk) + sB 16 KB = 24 KB -> 6 blocks/CU,
// 1563 blocks -> ~2x the resident waves of the 64-row version (gather is
// latency-bound; this is the lever).
// Gather: wave-per-node, 8 nodes/wave; 64 lanes = 4 neighbors x 16 granules.

__global__ __launch_bounds__(256) void layer_fused4(
    const half8* __restrict__ Xh, const int* __restrict__ deg,
    const int* __restrict__ offsets, const int* __restrict__ adj,
    const _Float16* __restrict__ Bimg, const float* __restrict__ bias,
    _Float16* __restrict__ Yh, int N) {
    __shared__ __align__(16) _Float16 sU[4096];  // m image (32x128) / x chunk
    __shared__ __align__(16) _Float16 sB[8192];  // B chunk hi(4096)+lo(4096)

    int tid = threadIdx.x;
    int w = tid >> 6;
    int lane = tid & 63;
    int l31 = lane & 31;
    int lhi = lane >> 5;
    int n0 = blockIdx.x * 32;

    // ---- Phase G: wave-per-node hi-only gather segment-max (8 nodes/wave) ----
    {
        int sub = lane >> 4;  // neighbor slot 0..3
        int lf = lane & 15;   // feature granule
        const _Float16 ni = (_Float16)(-INFINITY);
        const half8 ninf = {ni, ni, ni, ni, ni, ni, ni, ni};
        const half8 hz = {(_Float16)0.f, (_Float16)0.f, (_Float16)0.f, (_Float16)0.f,
                          (_Float16)0.f, (_Float16)0.f, (_Float16)0.f, (_Float16)0.f};
        // lanes 0..7 hold this wave's 8 nodes' e0/deg (others duplicate)
        int nd = n0 + w * 8 + (lane & 7);
        int ndc = nd < N ? nd : N - 1;
        int e0v = offsets[ndc];
        int degv = (nd < N) ? deg[ndc] : 0;

        for (int i = 0; i < 8; ++i) {
            int e0 = __shfl(e0v, i, 64);
            int d = __shfl(degv, i, 64);
            int row = w * 8 + i;
            half8 acc = ninf;
            for (int base = 0; base < d; base += 16) {
                half8 v[4];
#pragma unroll
                for (int q = 0; q < 4; ++q) {
                    int j = base + q * 4 + sub;
                    int idx = adj[e0 + (j < d ? j : d - 1)];
                    v[q] = Xh[(size_t)idx * 16 + lf];
                }
                acc = h8max(acc, h8max(h8max(v[0], v[1]), h8max(v[2], v[3])));
            }
            acc = h8max(acc, h8shfl_xor(acc, 16));
            acc = h8max(acc, h8shfl_xor(acc, 32));
            if (d == 0) acc = hz;
            if (sub == 0) *(half8*)&sU[row * 128 + (lf ^ (row & 15)) * 8] = acc;
        }
    }
    __syncthreads();

    f32x16 acc;
    {
        float bv = bias[w * 32 + l31];
#pragma unroll
        for (int r = 0; r < 16; ++r) acc[r] = bv;
    }

    int rl = l31;  // this lane's A row within the 32-row tile

    // ---- Pass 0: m @ Wl^T (A = m image) ----
    for (int kc4 = 0; kc4 < 4; ++kc4) {
        if (kc4) __syncthreads();
        {
            const half8* bsrc = (const half8*)(Bimg + (size_t)kc4 * 8192);
            half8* bdst = (half8*)sB;
#pragma unroll
            for (int i = 0; i < 4; ++i) bdst[tid + i * 256] = bsrc[tid + i * 256];
        }
        __syncthreads();
#pragma unroll
        for (int ks = 0; ks < 2; ++ks) {
            int g16 = kc4 * 4 + ks * 2 + lhi;
            int posA = g16 ^ (rl & 15);
            half8 ah = *(const half8*)&sU[rl * 128 + posA * 8];
            int n = w * 32 + l31;
            int gpc = ks * 2 + lhi;
            int posB = (gpc + (n & 3) + ((n >> 2) & 3)) & 3;
            half8 bh = *(const half8*)&sB[n * 32 + posB * 8];
            half8 bl2 = *(const half8*)&sB[4096 + n * 32 + posB * 8];
            acc = __builtin_amdgcn_mfma_f32_32x32x16_f16(ah, bh, acc, 0, 0, 0);
            acc = __builtin_amdgcn_mfma_f32_32x32x16_f16(ah, bl2, acc, 0, 0, 0);
        }
    }

    // ---- Pass 1: x @ Wr^T (x chunk staged into sU, stride-72) ----
    for (int kc4 = 0; kc4 < 4; ++kc4) {
        __syncthreads();
        {
            const half8* bsrc = (const half8*)(Bimg + 32768 + (size_t)kc4 * 8192);
            half8* bdst = (half8*)sB;
#pragma unroll
            for (int i = 0; i < 4; ++i) bdst[tid + i * 256] = bsrc[tid + i * 256];
        }
        if ((kc4 & 1) == 0) {
            int kc64 = kc4 >> 1;
            // 32 rows x 8 granules = 256 half8 -> one per thread
            int row = tid >> 3;  // [0,32)
            int gp8 = tid & 7;
            int n = n0 + row;
            half8 h = {(_Float16)0.f, (_Float16)0.f, (_Float16)0.f, (_Float16)0.f,
                       (_Float16)0.f, (_Float16)0.f, (_Float16)0.f, (_Float16)0.f};
            if (n < N) h = Xh[(size_t)n * 16 + kc64 * 8 + gp8];
            int pos8 = (gp8 + (row & 7) + ((row >> 3) & 7)) & 7;
            *(half8*)&sU[row * 72 + pos8 * 8] = h;
        }
        __syncthreads();
#pragma unroll
        for (int ks = 0; ks < 2; ++ks) {
            int gp8 = (kc4 & 1) * 4 + ks * 2 + lhi;
            int posA8 = (gp8 + (rl & 7) + ((rl >> 3) & 7)) & 7;
            half8 ah = *(const half8*)&sU[rl * 72 + posA8 * 8];
            int n = w * 32 + l31;
            int gpc = ks * 2 + lhi;
            int posB = (gpc + (n & 3) + ((n >> 2) & 3)) & 3;
            half8 bh = *(const half8*)&sB[n * 32 + posB * 8];
            half8 bl2 = *(const half8*)&sB[4096 + n * 32 + posB * 8];
            acc = __builtin_amdgcn_mfma_f32_32x32x16_f16(ah, bh, acc, 0, 0, 0);
            acc = __builtin_amdgcn_mfma_f32_32x32x16_f16(ah, bl2, acc, 0, 0, 0);
        }
    }

    // epilogue: relu + fp16 store. C/D: col=l31(+w*32), row=(r&3)+8*(r>>2)+4*lhi
#pragma unroll
    for (int r = 0; r < 16; ++r) {
        int row = n0 + (r & 3) + 8 * (r >> 2) + 4 * lhi;
        if (row < N) {
            int col = w * 32 + l31;
            Yh[(size_t)row * H + col] = (_Float16)fmaxf(acc[r], 0.f);
        }
    }
}

// ---------------- MFMA final linear + cosine, fp16-hi A ----------------
// Block 256 = 4 waves; each wave an independent 32-row stripe x 128 cols
// (nt=4). 128 rows/block. LDS: sA 18 KB (stride-72) + sB 16 KB = 34 KB.

__global__ __launch_bounds__(256) void final_mfma6(
    const half8* __restrict__ Xh, const _Float16* __restrict__ Bimg,  // Wlin
    const float* __restrict__ blin, const float* __restrict__ qn,
    const int* __restrict__ bv, float* __restrict__ out, int N) {
    __shared__ __align__(16) _Float16 sA[9216];  // 128 rows x stride 72
    __shared__ __align__(16) _Float16 sB[8192];

    int tid = threadIdx.x;
    int w = tid >> 6;
    int lane = tid & 63;
    int l31 = lane & 31;
    int lhi = lane >> 5;
    int n0 = blockIdx.x * 128;

    int arow = n0 + w * 32 + l31;
    arow = arow < N ? arow : N - 1;
    int gl = bv[arow];  // stripe's graph ids, indexed by l31

    f32x16 acc[4];
#pragma unroll
    for (int nt = 0; nt < 4; ++nt) {
        float b = blin[nt * 32 + l31];
#pragma unroll
        for (int r = 0; r < 16; ++r) acc[nt][r] = b;
    }

    int rl = w * 32 + l31;

    for (int kc4 = 0; kc4 < 4; ++kc4) {
        if (kc4) __syncthreads();
        {
            const half8* bsrc = (const half8*)(Bimg + (size_t)kc4 * 8192);
            half8* bdst = (half8*)sB;
#pragma unroll
            for (int i = 0; i < 4; ++i) bdst[tid + i * 256] = bsrc[tid + i * 256];
        }
        if ((kc4 & 1) == 0) {
            int kc64 = kc4 >> 1;
#pragma unroll
            for (int i = 0; i < 4; ++i) {
                int idx = tid + i * 256;  // [0,1024)
                int row = idx >> 3;       // [0,128)
                int gp8 = idx & 7;
                int n = n0 + row;
                half8 h = {(_Float16)0.f, (_Float16)0.f, (_Float16)0.f, (_Float16)0.f,
                           (_Float16)0.f, (_Float16)0.f, (_Float16)0.f, (_Float16)0.f};
                if (n < N) h = Xh[(size_t)n * 16 + kc64 * 8 + gp8];
                int pos8 = (gp8 + (row & 7) + ((row >> 3) & 7)) & 7;
                *(half8*)&sA[row * 72 + pos8 * 8] = h;
            }
        }
        __syncthreads();
#pragma unroll
        for (int ks = 0; ks < 2; ++ks) {
            int gp8 = (kc4 & 1) * 4 + ks * 2 + lhi;
            int posA8 = (gp8 + (rl & 7) + ((rl >> 3) & 7)) & 7;
            half8 ah = *(const half8*)&sA[rl * 72 + posA8 * 8];
#pragma unroll
            for (int nt = 0; nt < 4; ++nt) {
                int n = nt * 32 + l31;
                int gpc = ks * 2 + lhi;
                int posB = (gpc + (n & 3) + ((n >> 2) & 3)) & 3;
                half8 bh = *(const half8*)&sB[n * 32 + posB * 8];
                half8 bl2 = *(const half8*)&sB[4096 + n * 32 + posB * 8];
                acc[nt] = __builtin_amdgcn_mfma_f32_32x32x16_f16(ah, bh, acc[nt], 0, 0, 0);
                acc[nt] = __builtin_amdgcn_mfma_f32_32x32x16_f16(ah, bl2, acc[nt], 0, 0, 0);
            }
        }
    }

    // cosine epilogue: row rloc owned by 32 lanes (l31); xor<=16 stays in group
#pragma unroll
    for (int r = 0; r < 16; ++r) {
        int rloc = (r & 3) + 8 * (r >> 2) + 4 * lhi;
        int row = n0 + w * 32 + rloc;
        int g = __shfl(gl, rloc, 32);  // stripe-row rloc's graph id
        float ss = 0.f, sd = 0.f;
#pragma unroll
        for (int nt = 0; nt < 4; ++nt) {
            float y = acc[nt][r];
            float q = qn[(size_t)g * H + nt * 32 + l31];
            ss = fmaf(y, y, ss);
            sd = fmaf(y, q, sd);
        }
#pragma unroll
        for (int off = 1; off <= 16; off <<= 1) {
            ss += __shfl_xor(ss, off, 64);
            sd += __shfl_xor(sd, off, 64);
        }
        if (l31 == 0 && row < N) out[row] = sd / fmaxf(sqrtf(ss), 1e-12f);
    }
}

// ---------------- launch ----------------

extern "C" void kernel_launch(void* const* d_in, const int* in_sizes, int n_in,
                              void* d_out, int out_size, void* d_ws, size_t ws_size,
                              hipStream_t stream) {
    const float* x = (const float*)d_in[0];
    const float* query = (const float*)d_in[1];
    const float* Wl = (const float*)d_in[2];
    const float* bl = (const float*)d_in[3];
    const float* Wr = (const float*)d_in[4];
    const float* Wlin = (const float*)d_in[5];
    const float* blin = (const float*)d_in[6];
    const int* ei = (const int*)d_in[7];
    const int* bv = (const int*)d_in[8];
    float* out = (float*)d_out;

    const int N = in_sizes[0] / H;
    const int E = in_sizes[7] / 2;
    const int G = in_sizes[1] / H;

    char* p = (char*)d_ws;
    auto alloc = [&](size_t bytes) {
        char* r = p;
        p += (bytes + 255) & ~(size_t)255;
        return r;
    };
    int* deg = (int*)alloc((size_t)(2 * N + 1) * sizeof(int));  // deg|cursor|gcur
    int* cursor = deg + N;
    int* gcur = deg + 2 * N;
    int* offsets = (int*)alloc((size_t)N * sizeof(int));
    int* adj = (int*)alloc((size_t)E * sizeof(int));
    float* qn = (float*)alloc((size_t)G * H * sizeof(float));
    _Float16* wimg = (_Float16*)alloc((size_t)7 * 32768 * sizeof(_Float16));
    size_t actH = (size_t)N * H * sizeof(_Float16);
    _Float16* xah = (_Float16*)alloc(actH);
    _Float16* xbh = (_Float16*)alloc(actH);

    hipMemsetAsync(deg, 0, (size_t)(2 * N + 1) * sizeof(int), stream);

    const int n8 = N * H / 8;
    const int HB = (E + 255) / 256;
    const int SB = (n8 + 255) / 256;
    const int WB = (7 * 2048 + 255) / 256;
    prep_all<<<HB + SB + WB + G, 256, 0, stream>>>(ei, E, deg, x, query, Wl, Wr,
                                                   Wlin, xah, wimg, qn, n8, HB,
                                                   SB, WB);
    scan_atomic<<<(N + 255) / 256, 256, 0, stream>>>(deg, offsets, gcur, N);
    fill_adj<<<(E + 255) / 256, 256, 0, stream>>>(ei, E, offsets, cursor, adj);

    const int NGm = (N + 31) / 32;    // fused layer blocks (32-row tiles)
    const int NGf = (N + 127) / 128;  // final blocks

    layer_fused4<<<NGm, 256, 0, stream>>>(
        (const half8*)xah, deg, offsets, adj, wimg + (size_t)0 * 65536,
        bl + 0 * H, xbh, N);
    layer_fused4<<<NGm, 256, 0, stream>>>(
        (const half8*)xbh, deg, offsets, adj, wimg + (size_t)1 * 65536,
        bl + 1 * H, xah, N);
    layer_fused4<<<NGm, 256, 0, stream>>>(
        (const half8*)xah, deg, offsets, adj, wimg + (size_t)2 * 65536,
        bl + 2 * H, xbh, N);
    final_mfma6<<<NGf, 256, 0, stream>>>(
        (const half8*)xbh, wimg + (size_t)6 * 32768, blin, qn, bv, out, N);
}